// Round 14
// baseline (1478.543 us; speedup 1.0000x reference)
//
#include <hip/hip_runtime.h>

#define M_ROWS 16384
#define DIM    512
#define NCODES 8192

// ws layout (bytes) — 9.2 MB total
#define WS_X     0          // 16384 f32
#define WS_KEY   65536      // 16384 u64 packed (dist_bits<<32)|code
#define WS_PART  196608     // 2048 f64
#define WS_CNT   212992     // 256 u32 bucket counters + ticket at [256]
#define WS_CAND  217088     // [256][1024] u32 rows
#define WS_BMAX  1265664    // bmaxT: [4096 tasks][32 rows][16] u32 = 8 MB
#define NPART    2048
#define BCAP     1024
#define ENC_MARG 84         // 84 * 3.05e-6 ≈ 2.56e-4 dot margin (validated)

typedef __attribute__((ext_vector_type(8))) short bh8;   // 8 bf16
typedef __attribute__((ext_vector_type(4))) float f32x4;

__device__ __forceinline__ unsigned short bfc(float f) {  // RNE f32->bf16 bits
    unsigned u = __float_as_uint(f);
    return (unsigned short)((u + 0x7fffu + ((u >> 16) & 1u)) >> 16);
}
__device__ __forceinline__ unsigned short enc16(float d) { // monotone fixed-point
    float v = (d + 0.1f) * 327680.0f;
    int iv = (int)v;
    iv = iv < 0 ? 0 : (iv > 65535 ? 65535 : iv);
    return (unsigned short)iv;
}
__device__ __forceinline__ void gload16(const void* g, void* l) {
    __builtin_amdgcn_global_load_lds(
        (const __attribute__((address_space(1))) unsigned int*)g,
        (__attribute__((address_space(3))) unsigned int*)l, 16, 0, 0);
}

// ---------------- K0: init key + bucket counters + ticket ----------------
__global__ void k0_init(unsigned long long* __restrict__ key,
                        unsigned* __restrict__ cnt) {
    int i = blockIdx.x * blockDim.x + threadIdx.x;
    if (i < M_ROWS) key[i] = ~0ull;
    if (i <= 256) cnt[i] = 0u;      // 256 buckets + ticket
}

// ---------------- K1c: fused rowsum (bitwise numpy pairwise) + bf16 convert ----------
__global__ __launch_bounds__(256) void k1c(
    const float* __restrict__ x, const float* __restrict__ E,
    float* __restrict__ X, unsigned short* __restrict__ xbf,
    unsigned short* __restrict__ ebf)
{
    const int gid = blockIdx.x * blockDim.x + threadIdx.x;
    // phase 1: X = np.sum(x*x, axis=1), bitwise pairwise chain (validated)
    if (gid < M_ROWS) {
        const float* a = x + (size_t)gid * DIM;
        float b[4];
#pragma unroll
        for (int blk = 0; blk < 4; ++blk) {
            const float* p = a + blk * 128;
            float r[8];
#pragma unroll
            for (int j = 0; j < 8; ++j) r[j] = __fmul_rn(p[j], p[j]);
            for (int i = 8; i < 128; i += 8) {
#pragma unroll
                for (int j = 0; j < 8; ++j)
                    r[j] = __fadd_rn(r[j], __fmul_rn(p[i + j], p[i + j]));
            }
            b[blk] = __fadd_rn(__fadd_rn(__fadd_rn(r[0], r[1]), __fadd_rn(r[2], r[3])),
                               __fadd_rn(__fadd_rn(r[4], r[5]), __fadd_rn(r[6], r[7])));
        }
        X[gid] = __fadd_rn(__fadd_rn(b[0], b[1]), __fadd_rn(b[2], b[3]));
    }
    // phase 2: coalesced bf16 conversion (independent outputs)
    const int NX4 = M_ROWS * DIM / 4;
    const int NT  = NX4 + NCODES * DIM / 4;
    for (int i = gid; i < NT; i += gridDim.x * blockDim.x) {
        const float4* s; unsigned short* d; int o;
        if (i < NX4) { s = (const float4*)x; d = xbf; o = i; }
        else         { s = (const float4*)E; d = ebf; o = i - NX4; }
        float4 v = s[o];
        ushort4 u = make_ushort4(bfc(v.x), bfc(v.y), bfc(v.z), bfc(v.w));
        *(ushort4*)(d + (size_t)o * 4) = u;
    }
}

// ---------------- Kdot: 32-row panels (32KB LDS) -> 4 blocks/CU, ticket queue ----------
// 4096 tasks = 8 chunks (1024 codes) x 512 panels (32 rows), chunk-major.
// Inner loop = round-9 validated code with mi in {0,1}.
__global__ __launch_bounds__(512, 8) void kdot(
    const unsigned short* __restrict__ xbf, const unsigned short* __restrict__ ebf,
    unsigned* __restrict__ bmaxT, unsigned* __restrict__ ticket)
{
    __shared__ __align__(16) unsigned short As[32 * 512];  // 32 KiB, phys-swizzled
    __shared__ unsigned short lds_b16[32][32];             // 2 KiB result stage
    __shared__ int tsh;

    const int tid = threadIdx.x;
    const int w = tid >> 6, lane = tid & 63;
    const int lm = lane & 15, lh = lane >> 4;

    for (;;) {
        if (tid == 0) tsh = (int)atomicAdd(ticket, 1u);
        __syncthreads();                       // broadcast t; As/lds_b16 safe to reuse
        const int t = tsh;
        if (t >= 4096) break;
        const int chunk = t >> 9, panel = t & 511;
        const int row0 = panel * 32;
        const int c0 = chunk * 1024;

        // stage A panel: 2048 16B-chunks, 4 rounds; linear LDS dest,
        // inv-XOR-swizzled global source (validated pattern)
        for (int r4 = 0; r4 < 4; ++r4) {
            int q = r4 * 512 + tid;
            int row = q >> 6, cp = q & 63;
            gload16(xbf + (size_t)(row0 + row) * DIM + ((cp ^ (row & 7)) << 3),
                    (char*)As + (size_t)(r4 * 8192 + w * 1024));
        }
        __syncthreads();

        for (int pass = 0; pass < 4; ++pass) {
            const int cb = c0 + pass * 256 + w * 32;   // wave's 32-code group
            f32x4 acc[2][2];
            const f32x4 z = {0.f, 0.f, 0.f, 0.f};
#pragma unroll
            for (int mi = 0; mi < 2; ++mi) { acc[mi][0] = z; acc[mi][1] = z; }

            for (int kt = 0; kt < 16; ++kt) {
                bh8 a[2], b[2];
#pragma unroll
                for (int mi = 0; mi < 2; ++mi) {
                    int r = mi * 16 + lm;
                    int kc = kt * 4 + lh;
                    a[mi] = *(const bh8*)((const char*)As +
                                          (((r << 6) + (kc ^ (r & 7))) << 4));
                }
#pragma unroll
                for (int ni = 0; ni < 2; ++ni)
                    b[ni] = *(const bh8*)(ebf + (size_t)(cb + ni * 16 + lm) * DIM
                                          + kt * 32 + (lh << 3));
#pragma unroll
                for (int mi = 0; mi < 2; ++mi)
#pragma unroll
                    for (int ni = 0; ni < 2; ++ni)
                        acc[mi][ni] = __builtin_amdgcn_mfma_f32_16x16x32_bf16(
                            a[mi], b[ni], acc[mi][ni], 0, 0, 0);
            }
            // per-(row, 32-grp) max; identical fmax tree + 16-lane shfl reduce
            const int gidx = pass * 8 + w;             // 32-code group within chunk
#pragma unroll
            for (int mi = 0; mi < 2; ++mi)
#pragma unroll
                for (int reg = 0; reg < 4; ++reg) {
                    float m = fmaxf(acc[mi][0][reg], acc[mi][1][reg]);
#pragma unroll
                    for (int off = 1; off < 16; off <<= 1)
                        m = fmaxf(m, __shfl_xor(m, off));
                    if (lm == 0)
                        lds_b16[mi * 16 + lh * 4 + reg][gidx] = enc16(m);
                }
        }
        __syncthreads();
        // dense coalesced store: 2 KB contiguous per task (full lines, no RMW)
        const unsigned* lb = (const unsigned*)&lds_b16[0][0];
        if (tid < 512) bmaxT[(size_t)t * 512 + tid] = lb[tid];
    }
}

// ---------------- Kgmax: wave-per-row threshold -> bucketed (grp -> rows) ----------------
// bmaxT layout: task (chunk*512+panel32) stride 512 u32; [32 rows][16 u32 = 32 u16 grps]
__global__ __launch_bounds__(256) void kgmax(const unsigned* __restrict__ bmaxT,
                                             unsigned* __restrict__ cnt,
                                             unsigned* __restrict__ cand) {
    int gt = blockIdx.x * blockDim.x + threadIdx.x;
    int row = gt >> 6, lane = gt & 63;
    if (row >= M_ROWS) return;
    const int panel = row >> 5, r = row & 31;
    const int chunk = lane >> 3;                 // lane's 4 groups live in one chunk
    const size_t base = ((size_t)(chunk * 512 + panel) * 32 + r) * 16 + (lane & 7) * 2;
    unsigned w0 = bmaxT[base];
    unsigned w1 = bmaxT[base + 1];
    unsigned e[4] = {w0 & 0xffffu, w0 >> 16, w1 & 0xffffu, w1 >> 16};
    int      g0 = lane * 4;                      // groups lane*4 .. lane*4+3
    unsigned m = max(max(e[0], e[1]), max(e[2], e[3]));
#pragma unroll
    for (int off = 1; off < 64; off <<= 1) m = max(m, (unsigned)__shfl_xor((int)m, off));
    unsigned th = (m > ENC_MARG) ? m - ENC_MARG : 0u;
#pragma unroll
    for (int k = 0; k < 4; ++k)
        if (e[k] >= th) {
            unsigned pos = atomicAdd(cnt + g0 + k, 1u);
            if (pos < BCAP) cand[(g0 + k) * BCAP + pos] = (unsigned)row;
        }
}

// ---------------- Krescore: 1 block/bucket, coalesced staging, exact f32 chain ----------
// FMA chain (d=0..511, single acc) bitwise-identical to the validated sequence.
__global__ __launch_bounds__(512, 2) void krescore(
    const float* __restrict__ x, const float* __restrict__ E,
    const float* __restrict__ Xs, const unsigned* __restrict__ cnt,
    const unsigned* __restrict__ cand, unsigned long long* __restrict__ key)
{
    __shared__ float lds_e[512][33];   // 67.5 KiB padded: reads conflict-free
    const int b = blockIdx.x;
    const int t = threadIdx.x;
    {   // coalesced staging: consecutive threads read consecutive 16B of the slice
        const float4* Eb = (const float4*)(E + (size_t)b * 32 * DIM);  // 4096 float4
#pragma unroll
        for (int i = 0; i < 8; ++i) {
            int o = i * 512 + t;            // linear float4 index
            int r = o >> 7, c4 = o & 127;   // row, float4-col
            float4 v = Eb[o];
            lds_e[c4 * 4 + 0][r] = v.x; lds_e[c4 * 4 + 1][r] = v.y;
            lds_e[c4 * 4 + 2][r] = v.z; lds_e[c4 * 4 + 3][r] = v.w;
        }
    }
    __syncthreads();
    unsigned nb = cnt[b]; if (nb > BCAP) nb = BCAP;
    const int hw = t >> 5, l = t & 31;              // 16 lane-groups of 32
    for (unsigned p = (unsigned)hw; p < nb; p += 16) {
        int row = (int)cand[b * BCAP + p];
        const float4* __restrict__ xr = (const float4*)(x + (size_t)row * DIM);
        float acc = 0.f;
        for (int d0 = 0; d0 < 128; d0 += 8) {
            float4 xv[8];
#pragma unroll
            for (int j = 0; j < 8; ++j) xv[j] = xr[d0 + j];
#pragma unroll
            for (int j = 0; j < 8; ++j) {
                int d = (d0 + j) * 4;
                acc = __fmaf_rn(xv[j].x, lds_e[d + 0][l], acc);
                acc = __fmaf_rn(xv[j].y, lds_e[d + 1][l], acc);
                acc = __fmaf_rn(xv[j].z, lds_e[d + 2][l], acc);
                acc = __fmaf_rn(xv[j].w, lds_e[d + 3][l], acc);
            }
        }
        float dist = __fsub_rn(Xs[row], __fmul_rn(2.0f, acc));
        unsigned long long k =
            ((unsigned long long)__float_as_uint(dist) << 32) | (unsigned)(b * 32 + l);
#pragma unroll
        for (int off = 1; off < 32; off <<= 1) {
            unsigned long long o = __shfl_xor(k, off);
            k = o < k ? o : k;
        }
        if (l == 0) atomicMin(key + row, k);
    }
}

// ---------------- K3: gather outputs + loss partials + indices ----------------
__global__ __launch_bounds__(256) void k3_out(
    const float* __restrict__ x, const float* __restrict__ E,
    const unsigned long long* __restrict__ key, float* __restrict__ out0,
    float* __restrict__ out1, double* __restrict__ part,
    float* __restrict__ outIdx)
{
    const int n4 = M_ROWS * (DIM / 4);
    double loc = 0.0;
    for (int i4 = blockIdx.x * blockDim.x + threadIdx.x; i4 < n4;
         i4 += gridDim.x * blockDim.x) {
        int row = i4 >> 7;
        int d4  = i4 & 127;
        int idx = (int)(key[row] & 8191ull);
        if (d4 == 0) outIdx[row] = (float)idx;   // fold k2b: exactly once per row
        float4 xv = *(const float4*)(x + (size_t)i4 * 4);
        float4 qv = *(const float4*)(E + (size_t)idx * DIM + d4 * 4);
        float4 o0;
        float dx0 = __fsub_rn(qv.x, xv.x);
        float dx1 = __fsub_rn(qv.y, xv.y);
        float dx2 = __fsub_rn(qv.z, xv.z);
        float dx3 = __fsub_rn(qv.w, xv.w);
        o0.x = __fadd_rn(xv.x, dx0);
        o0.y = __fadd_rn(xv.y, dx1);
        o0.z = __fadd_rn(xv.z, dx2);
        o0.w = __fadd_rn(xv.w, dx3);
        *(float4*)(out0 + (size_t)i4 * 4) = o0;
        *(float4*)(out1 + (size_t)i4 * 4) = qv;
        loc += (double)__fmul_rn(dx0, dx0) + (double)__fmul_rn(dx1, dx1)
             + (double)__fmul_rn(dx2, dx2) + (double)__fmul_rn(dx3, dx3);
    }
#pragma unroll
    for (int off = 32; off > 0; off >>= 1) loc += __shfl_down(loc, off);
    __shared__ double wsum[4];
    int lane = threadIdx.x & 63, wid = threadIdx.x >> 6;
    if (lane == 0) wsum[wid] = loc;
    __syncthreads();
    if (threadIdx.x == 0)
        part[blockIdx.x] = (wsum[0] + wsum[1]) + (wsum[2] + wsum[3]);
}

// ---------------- K4: finalize losses ----------------
__global__ void k4_final(const double* __restrict__ part, float* __restrict__ outL) {
    __shared__ double s[256];
    double loc = 0.0;
    for (int i = threadIdx.x; i < NPART; i += 256) loc += part[i];
    s[threadIdx.x] = loc;
    __syncthreads();
    for (int st = 128; st > 0; st >>= 1) {
        if (threadIdx.x < st) s[threadIdx.x] += s[threadIdx.x + st];
        __syncthreads();
    }
    if (threadIdx.x == 0) {
        float m = (float)(s[0] / 8388608.0);
        outL[0] = m;
        outL[1] = m;
    }
}

extern "C" void kernel_launch(void* const* d_in, const int* in_sizes, int n_in,
                              void* d_out, int out_size, void* d_ws, size_t ws_size,
                              hipStream_t stream) {
    const float* x = (const float*)d_in[0];
    const float* E = (const float*)d_in[1];
    float* out = (float*)d_out;
    char* ws = (char*)d_ws;

    float* X                = (float*)(ws + WS_X);
    unsigned long long* key = (unsigned long long*)(ws + WS_KEY);
    double* part            = (double*)(ws + WS_PART);
    unsigned* cnt           = (unsigned*)(ws + WS_CNT);
    unsigned* ticket        = cnt + 256;
    unsigned* cand          = (unsigned*)(ws + WS_CAND);
    unsigned* bmaxT         = (unsigned*)(ws + WS_BMAX);

    float* out0   = out;               // quantized_ste
    float* out1   = out + 8388608;     // quantized
    float* outL   = out + 16777216;    // q_loss, e_loss
    float* outIdx = out + 16777218;    // indices as f32

    // bf16 staging buffers live inside out0's region (dead until k3_out rewrites it)
    unsigned short* xbf = (unsigned short*)out0;
    unsigned short* ebf = xbf + (size_t)M_ROWS * DIM;

    hipLaunchKernelGGL(k0_init,   dim3(64),   dim3(256), 0, stream, key, cnt);
    hipLaunchKernelGGL(k1c,       dim3(2048), dim3(256), 0, stream, x, E, X, xbf, ebf);
    hipLaunchKernelGGL(kdot,      dim3(1024), dim3(512), 0, stream, xbf, ebf, bmaxT, ticket);
    hipLaunchKernelGGL(kgmax,     dim3(4096), dim3(256), 0, stream, bmaxT, cnt, cand);
    hipLaunchKernelGGL(krescore,  dim3(256),  dim3(512), 0, stream, x, E, X, cnt, cand, key);
    hipLaunchKernelGGL(k3_out,    dim3(2048), dim3(256), 0, stream, x, E, key, out0, out1, part, outIdx);
    hipLaunchKernelGGL(k4_final,  dim3(1),    dim3(256), 0, stream, part, outL);
}

// Round 15
// 1064.055 us; speedup vs baseline: 1.3895x; 1.3895x over previous
//
#include <hip/hip_runtime.h>

#define M_ROWS 16384
#define DIM    512
#define NCODES 8192

// ws layout (bytes) — 9.2 MB total
#define WS_X     0          // 16384 f32
#define WS_KEY   65536      // 16384 u64 packed (dist_bits<<32)|code
#define WS_PART  196608     // 2048 f64
#define WS_CNT   212992     // 256 u32 bucket counters + ticket at [256]
#define WS_CAND  217088     // [256][1024] u32 rows
#define WS_BMAX  1265664    // bmaxT: [4096 tasks][32 rows][16] u32 = 8 MB
#define NPART    2048
#define BCAP     1024
#define ENC_MARG 84         // 84 * 3.05e-6 ≈ 2.56e-4 dot margin (validated)

typedef __attribute__((ext_vector_type(8))) short bh8;   // 8 bf16
typedef __attribute__((ext_vector_type(4))) float f32x4;

__device__ __forceinline__ unsigned short bfc(float f) {  // RNE f32->bf16 bits
    unsigned u = __float_as_uint(f);
    return (unsigned short)((u + 0x7fffu + ((u >> 16) & 1u)) >> 16);
}
__device__ __forceinline__ unsigned short enc16(float d) { // monotone fixed-point
    float v = (d + 0.1f) * 327680.0f;
    int iv = (int)v;
    iv = iv < 0 ? 0 : (iv > 65535 ? 65535 : iv);
    return (unsigned short)iv;
}
__device__ __forceinline__ void gload16(const void* g, void* l) {
    __builtin_amdgcn_global_load_lds(
        (const __attribute__((address_space(1))) unsigned int*)g,
        (__attribute__((address_space(3))) unsigned int*)l, 16, 0, 0);
}

// ---------------- K0: init key + bucket counters + ticket ----------------
__global__ void k0_init(unsigned long long* __restrict__ key,
                        unsigned* __restrict__ cnt) {
    int i = blockIdx.x * blockDim.x + threadIdx.x;
    if (i < M_ROWS) key[i] = ~0ull;
    if (i <= 256) cnt[i] = 0u;      // 256 buckets + ticket
}

// ---------------- K1c: fused rowsum (bitwise numpy pairwise) + bf16 convert ----------
__global__ __launch_bounds__(256) void k1c(
    const float* __restrict__ x, const float* __restrict__ E,
    float* __restrict__ X, unsigned short* __restrict__ xbf,
    unsigned short* __restrict__ ebf)
{
    const int gid = blockIdx.x * blockDim.x + threadIdx.x;
    // phase 1: X = np.sum(x*x, axis=1), bitwise pairwise chain (validated)
    if (gid < M_ROWS) {
        const float* a = x + (size_t)gid * DIM;
        float b[4];
#pragma unroll
        for (int blk = 0; blk < 4; ++blk) {
            const float* p = a + blk * 128;
            float r[8];
#pragma unroll
            for (int j = 0; j < 8; ++j) r[j] = __fmul_rn(p[j], p[j]);
            for (int i = 8; i < 128; i += 8) {
#pragma unroll
                for (int j = 0; j < 8; ++j)
                    r[j] = __fadd_rn(r[j], __fmul_rn(p[i + j], p[i + j]));
            }
            b[blk] = __fadd_rn(__fadd_rn(__fadd_rn(r[0], r[1]), __fadd_rn(r[2], r[3])),
                               __fadd_rn(__fadd_rn(r[4], r[5]), __fadd_rn(r[6], r[7])));
        }
        X[gid] = __fadd_rn(__fadd_rn(b[0], b[1]), __fadd_rn(b[2], b[3]));
    }
    // phase 2: coalesced bf16 conversion (independent outputs)
    const int NX4 = M_ROWS * DIM / 4;
    const int NT  = NX4 + NCODES * DIM / 4;
    for (int i = gid; i < NT; i += gridDim.x * blockDim.x) {
        const float4* s; unsigned short* d; int o;
        if (i < NX4) { s = (const float4*)x; d = xbf; o = i; }
        else         { s = (const float4*)E; d = ebf; o = i - NX4; }
        float4 v = s[o];
        ushort4 u = make_ushort4(bfc(v.x), bfc(v.y), bfc(v.z), bfc(v.w));
        *(ushort4*)(d + (size_t)o * 4) = u;
    }
}

// ---------------- Kdot: 32-row panels (35KB LDS, 4 blocks/CU), (512,4) bounds ----------
// 4096 tasks = 8 chunks (1024 codes) x 512 panels (32 rows), chunk-major ticket.
// Inner loop = round-9 validated code with mi in {0,1}. (512,4): proven no-spill.
__global__ __launch_bounds__(512, 4) void kdot(
    const unsigned short* __restrict__ xbf, const unsigned short* __restrict__ ebf,
    unsigned* __restrict__ bmaxT, unsigned* __restrict__ ticket)
{
    __shared__ __align__(16) unsigned short As[32 * 512];  // 32 KiB, phys-swizzled
    __shared__ unsigned short lds_b16[32][32];             // 2 KiB result stage
    __shared__ int tsh;

    const int tid = threadIdx.x;
    const int w = tid >> 6, lane = tid & 63;
    const int lm = lane & 15, lh = lane >> 4;

    for (;;) {
        if (tid == 0) tsh = (int)atomicAdd(ticket, 1u);
        __syncthreads();                       // broadcast t; As/lds_b16 safe to reuse
        const int t = tsh;
        if (t >= 4096) break;
        const int chunk = t >> 9, panel = t & 511;
        const int row0 = panel * 32;
        const int c0 = chunk * 1024;

        // stage A panel: 2048 16B-chunks, 4 rounds; linear LDS dest,
        // inv-XOR-swizzled global source (validated pattern)
        for (int r4 = 0; r4 < 4; ++r4) {
            int q = r4 * 512 + tid;
            int row = q >> 6, cp = q & 63;
            gload16(xbf + (size_t)(row0 + row) * DIM + ((cp ^ (row & 7)) << 3),
                    (char*)As + (size_t)(r4 * 8192 + w * 1024));
        }
        __syncthreads();

        for (int pass = 0; pass < 4; ++pass) {
            const int cb = c0 + pass * 256 + w * 32;   // wave's 32-code group
            f32x4 acc[2][2];
            const f32x4 z = {0.f, 0.f, 0.f, 0.f};
#pragma unroll
            for (int mi = 0; mi < 2; ++mi) { acc[mi][0] = z; acc[mi][1] = z; }

            for (int kt = 0; kt < 16; ++kt) {
                bh8 a[2], b[2];
#pragma unroll
                for (int mi = 0; mi < 2; ++mi) {
                    int r = mi * 16 + lm;
                    int kc = kt * 4 + lh;
                    a[mi] = *(const bh8*)((const char*)As +
                                          (((r << 6) + (kc ^ (r & 7))) << 4));
                }
#pragma unroll
                for (int ni = 0; ni < 2; ++ni)
                    b[ni] = *(const bh8*)(ebf + (size_t)(cb + ni * 16 + lm) * DIM
                                          + kt * 32 + (lh << 3));
#pragma unroll
                for (int mi = 0; mi < 2; ++mi)
#pragma unroll
                    for (int ni = 0; ni < 2; ++ni)
                        acc[mi][ni] = __builtin_amdgcn_mfma_f32_16x16x32_bf16(
                            a[mi], b[ni], acc[mi][ni], 0, 0, 0);
            }
            // per-(row, 32-grp) max; identical fmax tree + 16-lane shfl reduce
            const int gidx = pass * 8 + w;             // 32-code group within chunk
#pragma unroll
            for (int mi = 0; mi < 2; ++mi)
#pragma unroll
                for (int reg = 0; reg < 4; ++reg) {
                    float m = fmaxf(acc[mi][0][reg], acc[mi][1][reg]);
#pragma unroll
                    for (int off = 1; off < 16; off <<= 1)
                        m = fmaxf(m, __shfl_xor(m, off));
                    if (lm == 0)
                        lds_b16[mi * 16 + lh * 4 + reg][gidx] = enc16(m);
                }
        }
        __syncthreads();
        // dense coalesced store: 2 KB contiguous per task (full lines, no RMW)
        const unsigned* lb = (const unsigned*)&lds_b16[0][0];
        if (tid < 512) bmaxT[(size_t)t * 512 + tid] = lb[tid];
    }
}

// ---------------- Kgmax: wave-per-row threshold -> bucketed (grp -> rows) ----------------
// bmaxT layout: task (chunk*512+panel32) stride 512 u32; [32 rows][16 u32 = 32 u16 grps]
__global__ __launch_bounds__(256) void kgmax(const unsigned* __restrict__ bmaxT,
                                             unsigned* __restrict__ cnt,
                                             unsigned* __restrict__ cand) {
    int gt = blockIdx.x * blockDim.x + threadIdx.x;
    int row = gt >> 6, lane = gt & 63;
    if (row >= M_ROWS) return;
    const int panel = row >> 5, r = row & 31;
    const int chunk = lane >> 3;                 // lane's 4 groups live in one chunk
    const size_t base = ((size_t)(chunk * 512 + panel) * 32 + r) * 16 + (lane & 7) * 2;
    unsigned w0 = bmaxT[base];
    unsigned w1 = bmaxT[base + 1];
    unsigned e[4] = {w0 & 0xffffu, w0 >> 16, w1 & 0xffffu, w1 >> 16};
    int      g0 = lane * 4;                      // groups lane*4 .. lane*4+3
    unsigned m = max(max(e[0], e[1]), max(e[2], e[3]));
#pragma unroll
    for (int off = 1; off < 64; off <<= 1) m = max(m, (unsigned)__shfl_xor((int)m, off));
    unsigned th = (m > ENC_MARG) ? m - ENC_MARG : 0u;
#pragma unroll
    for (int k = 0; k < 4; ++k)
        if (e[k] >= th) {
            unsigned pos = atomicAdd(cnt + g0 + k, 1u);
            if (pos < BCAP) cand[(g0 + k) * BCAP + pos] = (unsigned)row;
        }
}

// ---------------- Krescore: 1 block/bucket, coalesced staging, exact f32 chain ----------
// FMA chain (d=0..511, single acc) bitwise-identical to the validated sequence.
__global__ __launch_bounds__(512, 2) void krescore(
    const float* __restrict__ x, const float* __restrict__ E,
    const float* __restrict__ Xs, const unsigned* __restrict__ cnt,
    const unsigned* __restrict__ cand, unsigned long long* __restrict__ key)
{
    __shared__ float lds_e[512][33];   // 67.5 KiB padded: reads conflict-free
    const int b = blockIdx.x;
    const int t = threadIdx.x;
    {   // coalesced staging: consecutive threads read consecutive 16B of the slice
        const float4* Eb = (const float4*)(E + (size_t)b * 32 * DIM);  // 4096 float4
#pragma unroll
        for (int i = 0; i < 8; ++i) {
            int o = i * 512 + t;            // linear float4 index
            int r = o >> 7, c4 = o & 127;   // row, float4-col
            float4 v = Eb[o];
            lds_e[c4 * 4 + 0][r] = v.x; lds_e[c4 * 4 + 1][r] = v.y;
            lds_e[c4 * 4 + 2][r] = v.z; lds_e[c4 * 4 + 3][r] = v.w;
        }
    }
    __syncthreads();
    unsigned nb = cnt[b]; if (nb > BCAP) nb = BCAP;
    const int hw = t >> 5, l = t & 31;              // 16 lane-groups of 32
    for (unsigned p = (unsigned)hw; p < nb; p += 16) {
        int row = (int)cand[b * BCAP + p];
        const float4* __restrict__ xr = (const float4*)(x + (size_t)row * DIM);
        float acc = 0.f;
        for (int d0 = 0; d0 < 128; d0 += 8) {
            float4 xv[8];
#pragma unroll
            for (int j = 0; j < 8; ++j) xv[j] = xr[d0 + j];
#pragma unroll
            for (int j = 0; j < 8; ++j) {
                int d = (d0 + j) * 4;
                acc = __fmaf_rn(xv[j].x, lds_e[d + 0][l], acc);
                acc = __fmaf_rn(xv[j].y, lds_e[d + 1][l], acc);
                acc = __fmaf_rn(xv[j].z, lds_e[d + 2][l], acc);
                acc = __fmaf_rn(xv[j].w, lds_e[d + 3][l], acc);
            }
        }
        float dist = __fsub_rn(Xs[row], __fmul_rn(2.0f, acc));
        unsigned long long k =
            ((unsigned long long)__float_as_uint(dist) << 32) | (unsigned)(b * 32 + l);
#pragma unroll
        for (int off = 1; off < 32; off <<= 1) {
            unsigned long long o = __shfl_xor(k, off);
            k = o < k ? o : k;
        }
        if (l == 0) atomicMin(key + row, k);
    }
}

// ---------------- K3: gather outputs + loss partials + indices ----------------
__global__ __launch_bounds__(256) void k3_out(
    const float* __restrict__ x, const float* __restrict__ E,
    const unsigned long long* __restrict__ key, float* __restrict__ out0,
    float* __restrict__ out1, double* __restrict__ part,
    float* __restrict__ outIdx)
{
    const int n4 = M_ROWS * (DIM / 4);
    double loc = 0.0;
    for (int i4 = blockIdx.x * blockDim.x + threadIdx.x; i4 < n4;
         i4 += gridDim.x * blockDim.x) {
        int row = i4 >> 7;
        int d4  = i4 & 127;
        int idx = (int)(key[row] & 8191ull);
        if (d4 == 0) outIdx[row] = (float)idx;   // fold k2b: exactly once per row
        float4 xv = *(const float4*)(x + (size_t)i4 * 4);
        float4 qv = *(const float4*)(E + (size_t)idx * DIM + d4 * 4);
        float4 o0;
        float dx0 = __fsub_rn(qv.x, xv.x);
        float dx1 = __fsub_rn(qv.y, xv.y);
        float dx2 = __fsub_rn(qv.z, xv.z);
        float dx3 = __fsub_rn(qv.w, xv.w);
        o0.x = __fadd_rn(xv.x, dx0);
        o0.y = __fadd_rn(xv.y, dx1);
        o0.z = __fadd_rn(xv.z, dx2);
        o0.w = __fadd_rn(xv.w, dx3);
        *(float4*)(out0 + (size_t)i4 * 4) = o0;
        *(float4*)(out1 + (size_t)i4 * 4) = qv;
        loc += (double)__fmul_rn(dx0, dx0) + (double)__fmul_rn(dx1, dx1)
             + (double)__fmul_rn(dx2, dx2) + (double)__fmul_rn(dx3, dx3);
    }
#pragma unroll
    for (int off = 32; off > 0; off >>= 1) loc += __shfl_down(loc, off);
    __shared__ double wsum[4];
    int lane = threadIdx.x & 63, wid = threadIdx.x >> 6;
    if (lane == 0) wsum[wid] = loc;
    __syncthreads();
    if (threadIdx.x == 0)
        part[blockIdx.x] = (wsum[0] + wsum[1]) + (wsum[2] + wsum[3]);
}

// ---------------- K4: finalize losses ----------------
__global__ void k4_final(const double* __restrict__ part, float* __restrict__ outL) {
    __shared__ double s[256];
    double loc = 0.0;
    for (int i = threadIdx.x; i < NPART; i += 256) loc += part[i];
    s[threadIdx.x] = loc;
    __syncthreads();
    for (int st = 128; st > 0; st >>= 1) {
        if (threadIdx.x < st) s[threadIdx.x] += s[threadIdx.x + st];
        __syncthreads();
    }
    if (threadIdx.x == 0) {
        float m = (float)(s[0] / 8388608.0);
        outL[0] = m;
        outL[1] = m;
    }
}

extern "C" void kernel_launch(void* const* d_in, const int* in_sizes, int n_in,
                              void* d_out, int out_size, void* d_ws, size_t ws_size,
                              hipStream_t stream) {
    const float* x = (const float*)d_in[0];
    const float* E = (const float*)d_in[1];
    float* out = (float*)d_out;
    char* ws = (char*)d_ws;

    float* X                = (float*)(ws + WS_X);
    unsigned long long* key = (unsigned long long*)(ws + WS_KEY);
    double* part            = (double*)(ws + WS_PART);
    unsigned* cnt           = (unsigned*)(ws + WS_CNT);
    unsigned* ticket        = cnt + 256;
    unsigned* cand          = (unsigned*)(ws + WS_CAND);
    unsigned* bmaxT         = (unsigned*)(ws + WS_BMAX);

    float* out0   = out;               // quantized_ste
    float* out1   = out + 8388608;     // quantized
    float* outL   = out + 16777216;    // q_loss, e_loss
    float* outIdx = out + 16777218;    // indices as f32

    // bf16 staging buffers live inside out0's region (dead until k3_out rewrites it)
    unsigned short* xbf = (unsigned short*)out0;
    unsigned short* ebf = xbf + (size_t)M_ROWS * DIM;

    hipLaunchKernelGGL(k0_init,   dim3(64),   dim3(256), 0, stream, key, cnt);
    hipLaunchKernelGGL(k1c,       dim3(2048), dim3(256), 0, stream, x, E, X, xbf, ebf);
    hipLaunchKernelGGL(kdot,      dim3(1024), dim3(512), 0, stream, xbf, ebf, bmaxT, ticket);
    hipLaunchKernelGGL(kgmax,     dim3(4096), dim3(256), 0, stream, bmaxT, cnt, cand);
    hipLaunchKernelGGL(krescore,  dim3(256),  dim3(512), 0, stream, x, E, X, cnt, cand, key);
    hipLaunchKernelGGL(k3_out,    dim3(2048), dim3(256), 0, stream, x, E, key, out0, out1, part, outIdx);
    hipLaunchKernelGGL(k4_final,  dim3(1),    dim3(256), 0, stream, part, outL);
}

// Round 16
// 636.671 us; speedup vs baseline: 2.3223x; 1.6713x over previous
//
#include <hip/hip_runtime.h>

#define M_ROWS 16384
#define DIM    512
#define NCODES 8192

// ws layout (bytes) — 9.2 MB total
#define WS_X     0          // 16384 f32
#define WS_KEY   65536      // 16384 u64 packed (dist_bits<<32)|code
#define WS_PART  196608     // 2048 f64
#define WS_CNT   212992     // 256 u32 bucket counters + ticket[256] + done[257]
#define WS_CAND  217088     // [256][1024] u32 rows
#define WS_BMAX  1265664    // bmaxT: [2048 tasks][64 rows][16] u32 = 8 MB
#define NPART    2048
#define BCAP     1024
#define ENC_MARG 84         // 84 * 3.05e-6 ≈ 2.56e-4 dot margin (validated)

typedef __attribute__((ext_vector_type(8))) short bh8;   // 8 bf16
typedef __attribute__((ext_vector_type(4))) float f32x4;

__device__ __forceinline__ unsigned short bfc(float f) {  // RNE f32->bf16 bits
    unsigned u = __float_as_uint(f);
    return (unsigned short)((u + 0x7fffu + ((u >> 16) & 1u)) >> 16);
}
__device__ __forceinline__ unsigned short enc16(float d) { // monotone fixed-point
    float v = (d + 0.1f) * 327680.0f;
    int iv = (int)v;
    iv = iv < 0 ? 0 : (iv > 65535 ? 65535 : iv);
    return (unsigned short)iv;
}
__device__ __forceinline__ void gload16(const void* g, void* l) {
    __builtin_amdgcn_global_load_lds(
        (const __attribute__((address_space(1))) unsigned int*)g,
        (__attribute__((address_space(3))) unsigned int*)l, 16, 0, 0);
}

// ---------------- K1c: init + fused rowsum (bitwise numpy pairwise) + bf16 convert ----
__global__ __launch_bounds__(256) void k1c(
    const float* __restrict__ x, const float* __restrict__ E,
    float* __restrict__ X, unsigned short* __restrict__ xbf,
    unsigned short* __restrict__ ebf, unsigned long long* __restrict__ key,
    unsigned* __restrict__ cnt)
{
    const int gid = blockIdx.x * blockDim.x + threadIdx.x;
    // phase 0: init (folded k0): key, bucket counters, ticket, done
    if (gid < M_ROWS) key[gid] = ~0ull;
    if (gid <= 257) cnt[gid] = 0u;
    // phase 1: X = np.sum(x*x, axis=1), bitwise pairwise chain (validated)
    if (gid < M_ROWS) {
        const float* a = x + (size_t)gid * DIM;
        float b[4];
#pragma unroll
        for (int blk = 0; blk < 4; ++blk) {
            const float* p = a + blk * 128;
            float r[8];
#pragma unroll
            for (int j = 0; j < 8; ++j) r[j] = __fmul_rn(p[j], p[j]);
            for (int i = 8; i < 128; i += 8) {
#pragma unroll
                for (int j = 0; j < 8; ++j)
                    r[j] = __fadd_rn(r[j], __fmul_rn(p[i + j], p[i + j]));
            }
            b[blk] = __fadd_rn(__fadd_rn(__fadd_rn(r[0], r[1]), __fadd_rn(r[2], r[3])),
                               __fadd_rn(__fadd_rn(r[4], r[5]), __fadd_rn(r[6], r[7])));
        }
        X[gid] = __fadd_rn(__fadd_rn(b[0], b[1]), __fadd_rn(b[2], b[3]));
    }
    // phase 2: coalesced bf16 conversion (independent outputs)
    const int NX4 = M_ROWS * DIM / 4;
    const int NT  = NX4 + NCODES * DIM / 4;
    for (int i = gid; i < NT; i += gridDim.x * blockDim.x) {
        const float4* s; unsigned short* d; int o;
        if (i < NX4) { s = (const float4*)x; d = xbf; o = i; }
        else         { s = (const float4*)E; d = ebf; o = i - NX4; }
        float4 v = s[o];
        ushort4 u = make_ushort4(bfc(v.x), bfc(v.y), bfc(v.z), bfc(v.w));
        *(ushort4*)(d + (size_t)o * 4) = u;
    }
}

// ---------------- Kdot: round-13 version verbatim (measured optimum, 278 us) ----------
// 2048 tasks = 8 chunks (1024 codes) x 256 panels (64 rows), chunk-major ticket.
__global__ __launch_bounds__(512, 4) void kdot(
    const unsigned short* __restrict__ xbf, const unsigned short* __restrict__ ebf,
    unsigned* __restrict__ bmaxT, unsigned* __restrict__ ticket)
{
    __shared__ __align__(16) unsigned short As[64 * 512];  // 64 KiB, phys-swizzled
    __shared__ unsigned short lds_b16[64][32];             // 4 KiB result stage
    __shared__ int tsh;

    const int tid = threadIdx.x;
    const int w = tid >> 6, lane = tid & 63;
    const int lm = lane & 15, lh = lane >> 4;

    for (;;) {
        if (tid == 0) tsh = (int)atomicAdd(ticket, 1u);
        __syncthreads();                       // broadcast t; As/lds_b16 safe to reuse
        const int t = tsh;
        if (t >= 2048) break;
        const int chunk = t >> 8, panel = t & 255;
        const int row0 = panel * 64;
        const int c0 = chunk * 1024;

        // stage A panel (validated): linear LDS dest, inv-XOR-swizzled source
        for (int r8 = 0; r8 < 8; ++r8) {
            int q = r8 * 512 + tid;
            int row = q >> 6, cp = q & 63;
            gload16(xbf + (size_t)(row0 + row) * DIM + ((cp ^ (row & 7)) << 3),
                    (char*)As + (size_t)(r8 * 8192 + w * 1024));
        }
        __syncthreads();

        for (int pass = 0; pass < 4; ++pass) {
            const int cb = c0 + pass * 256 + w * 32;   // wave's 32-code group
            f32x4 acc[4][2];
            const f32x4 z = {0.f, 0.f, 0.f, 0.f};
#pragma unroll
            for (int mi = 0; mi < 4; ++mi) { acc[mi][0] = z; acc[mi][1] = z; }

            for (int kt = 0; kt < 16; ++kt) {
                bh8 a[4], b[2];
#pragma unroll
                for (int mi = 0; mi < 4; ++mi) {
                    int r = mi * 16 + lm;
                    int kc = kt * 4 + lh;
                    a[mi] = *(const bh8*)((const char*)As +
                                          (((r << 6) + (kc ^ (r & 7))) << 4));
                }
#pragma unroll
                for (int ni = 0; ni < 2; ++ni)
                    b[ni] = *(const bh8*)(ebf + (size_t)(cb + ni * 16 + lm) * DIM
                                          + kt * 32 + (lh << 3));
#pragma unroll
                for (int mi = 0; mi < 4; ++mi)
#pragma unroll
                    for (int ni = 0; ni < 2; ++ni)
                        acc[mi][ni] = __builtin_amdgcn_mfma_f32_16x16x32_bf16(
                            a[mi], b[ni], acc[mi][ni], 0, 0, 0);
            }
            // per-(row, 32-grp) max; identical fmax tree + 16-lane shfl reduce
            const int gidx = pass * 8 + w;             // 32-code group within chunk
#pragma unroll
            for (int mi = 0; mi < 4; ++mi)
#pragma unroll
                for (int reg = 0; reg < 4; ++reg) {
                    float m = fmaxf(acc[mi][0][reg], acc[mi][1][reg]);
#pragma unroll
                    for (int off = 1; off < 16; off <<= 1)
                        m = fmaxf(m, __shfl_xor(m, off));
                    if (lm == 0)
                        lds_b16[mi * 16 + lh * 4 + reg][gidx] = enc16(m);
                }
        }
        __syncthreads();
        // dense coalesced store: 4 KB contiguous per task (full lines, no RMW)
        const unsigned* lb = (const unsigned*)&lds_b16[0][0];
#pragma unroll
        for (int k = 0; k < 2; ++k) {
            int i = k * 512 + tid;
            bmaxT[(size_t)t * 1024 + i] = lb[i];
        }
    }
}

// ---------------- Kgmax: round-13 version verbatim ----------------
__global__ __launch_bounds__(256) void kgmax(const unsigned* __restrict__ bmaxT,
                                             unsigned* __restrict__ cnt,
                                             unsigned* __restrict__ cand) {
    int gt = blockIdx.x * blockDim.x + threadIdx.x;
    int row = gt >> 6, lane = gt & 63;
    if (row >= M_ROWS) return;
    const int panel = row >> 6, r = row & 63;
    const int c0 = lane >> 4, gl = lane & 15;
    unsigned w0 = bmaxT[(size_t)(((c0    ) * 256 + panel) * 64 + r) * 16 + gl];
    unsigned w1 = bmaxT[(size_t)(((c0 + 4) * 256 + panel) * 64 + r) * 16 + gl];
    unsigned e[4] = {w0 & 0xffffu, w0 >> 16, w1 & 0xffffu, w1 >> 16};
    int      g[4] = {c0 * 32 + 2 * gl, c0 * 32 + 2 * gl + 1,
                     (c0 + 4) * 32 + 2 * gl, (c0 + 4) * 32 + 2 * gl + 1};
    unsigned m = max(max(e[0], e[1]), max(e[2], e[3]));
#pragma unroll
    for (int off = 1; off < 64; off <<= 1) m = max(m, (unsigned)__shfl_xor((int)m, off));
    unsigned th = (m > ENC_MARG) ? m - ENC_MARG : 0u;
#pragma unroll
    for (int k = 0; k < 4; ++k)
        if (e[k] >= th) {
            unsigned pos = atomicAdd(cnt + g[k], 1u);
            if (pos < BCAP) cand[g[k] * BCAP + pos] = (unsigned)row;
        }
}

// ---------------- Krescore: 1 block/bucket, coalesced staging, exact f32 chain ----------
// FMA chain (d=0..511, single acc) bitwise-identical to the validated sequence.
__global__ __launch_bounds__(512, 2) void krescore(
    const float* __restrict__ x, const float* __restrict__ E,
    const float* __restrict__ Xs, const unsigned* __restrict__ cnt,
    const unsigned* __restrict__ cand, unsigned long long* __restrict__ key)
{
    __shared__ float lds_e[512][33];   // 67.5 KiB padded: reads conflict-free
    const int b = blockIdx.x;
    const int t = threadIdx.x;
    {   // coalesced staging: consecutive threads read consecutive 16B of the slice
        const float4* Eb = (const float4*)(E + (size_t)b * 32 * DIM);  // 4096 float4
#pragma unroll
        for (int i = 0; i < 8; ++i) {
            int o = i * 512 + t;            // linear float4 index
            int r = o >> 7, c4 = o & 127;   // row, float4-col
            float4 v = Eb[o];
            lds_e[c4 * 4 + 0][r] = v.x; lds_e[c4 * 4 + 1][r] = v.y;
            lds_e[c4 * 4 + 2][r] = v.z; lds_e[c4 * 4 + 3][r] = v.w;
        }
    }
    __syncthreads();
    unsigned nb = cnt[b]; if (nb > BCAP) nb = BCAP;
    const int hw = t >> 5, l = t & 31;              // 16 lane-groups of 32
    for (unsigned p = (unsigned)hw; p < nb; p += 16) {
        int row = (int)cand[b * BCAP + p];
        const float4* __restrict__ xr = (const float4*)(x + (size_t)row * DIM);
        float acc = 0.f;
        for (int d0 = 0; d0 < 128; d0 += 8) {
            float4 xv[8];
#pragma unroll
            for (int j = 0; j < 8; ++j) xv[j] = xr[d0 + j];
#pragma unroll
            for (int j = 0; j < 8; ++j) {
                int d = (d0 + j) * 4;
                acc = __fmaf_rn(xv[j].x, lds_e[d + 0][l], acc);
                acc = __fmaf_rn(xv[j].y, lds_e[d + 1][l], acc);
                acc = __fmaf_rn(xv[j].z, lds_e[d + 2][l], acc);
                acc = __fmaf_rn(xv[j].w, lds_e[d + 3][l], acc);
            }
        }
        float dist = __fsub_rn(Xs[row], __fmul_rn(2.0f, acc));
        unsigned long long k =
            ((unsigned long long)__float_as_uint(dist) << 32) | (unsigned)(b * 32 + l);
#pragma unroll
        for (int off = 1; off < 32; off <<= 1) {
            unsigned long long o = __shfl_xor(k, off);
            k = o < k ? o : k;
        }
        if (l == 0) atomicMin(key + row, k);
    }
}

// ---------------- K3: gather outputs + losses + indices + folded final reduce ----------
__global__ __launch_bounds__(256) void k3_out(
    const float* __restrict__ x, const float* __restrict__ E,
    const unsigned long long* __restrict__ key, float* __restrict__ out0,
    float* __restrict__ out1, double* __restrict__ part,
    float* __restrict__ outIdx, unsigned* __restrict__ done,
    float* __restrict__ outL)
{
    const int n4 = M_ROWS * (DIM / 4);
    double loc = 0.0;
    for (int i4 = blockIdx.x * blockDim.x + threadIdx.x; i4 < n4;
         i4 += gridDim.x * blockDim.x) {
        int row = i4 >> 7;
        int d4  = i4 & 127;
        int idx = (int)(key[row] & 8191ull);
        if (d4 == 0) outIdx[row] = (float)idx;   // fold k2b: exactly once per row
        float4 xv = *(const float4*)(x + (size_t)i4 * 4);
        float4 qv = *(const float4*)(E + (size_t)idx * DIM + d4 * 4);
        float4 o0;
        float dx0 = __fsub_rn(qv.x, xv.x);
        float dx1 = __fsub_rn(qv.y, xv.y);
        float dx2 = __fsub_rn(qv.z, xv.z);
        float dx3 = __fsub_rn(qv.w, xv.w);
        o0.x = __fadd_rn(xv.x, dx0);
        o0.y = __fadd_rn(xv.y, dx1);
        o0.z = __fadd_rn(xv.z, dx2);
        o0.w = __fadd_rn(xv.w, dx3);
        *(float4*)(out0 + (size_t)i4 * 4) = o0;
        *(float4*)(out1 + (size_t)i4 * 4) = qv;
        loc += (double)__fmul_rn(dx0, dx0) + (double)__fmul_rn(dx1, dx1)
             + (double)__fmul_rn(dx2, dx2) + (double)__fmul_rn(dx3, dx3);
    }
#pragma unroll
    for (int off = 32; off > 0; off >>= 1) loc += __shfl_down(loc, off);
    __shared__ double wsum[4];
    __shared__ bool isLast;
    int lane = threadIdx.x & 63, wid = threadIdx.x >> 6;
    if (lane == 0) wsum[wid] = loc;
    __syncthreads();
    if (threadIdx.x == 0) {
        part[blockIdx.x] = (wsum[0] + wsum[1]) + (wsum[2] + wsum[3]);
        __threadfence();                          // make part visible device-wide
        unsigned v = atomicAdd(done, 1u);
        isLast = (v == (unsigned)gridDim.x - 1u);
    }
    __syncthreads();
    if (isLast) {                                  // folded k4: identical reduction order
        __shared__ double s[256];
        volatile const double* vp = part;          // L1-bypass reads (sc0)
        double l2 = 0.0;
        for (int i = threadIdx.x; i < NPART; i += 256) l2 += vp[i];
        s[threadIdx.x] = l2;
        __syncthreads();
        for (int st = 128; st > 0; st >>= 1) {
            if (threadIdx.x < st) s[threadIdx.x] += s[threadIdx.x + st];
            __syncthreads();
        }
        if (threadIdx.x == 0) {
            float m = (float)(s[0] / 8388608.0);
            outL[0] = m;
            outL[1] = m;
        }
    }
}

extern "C" void kernel_launch(void* const* d_in, const int* in_sizes, int n_in,
                              void* d_out, int out_size, void* d_ws, size_t ws_size,
                              hipStream_t stream) {
    const float* x = (const float*)d_in[0];
    const float* E = (const float*)d_in[1];
    float* out = (float*)d_out;
    char* ws = (char*)d_ws;

    float* X                = (float*)(ws + WS_X);
    unsigned long long* key = (unsigned long long*)(ws + WS_KEY);
    double* part            = (double*)(ws + WS_PART);
    unsigned* cnt           = (unsigned*)(ws + WS_CNT);
    unsigned* ticket        = cnt + 256;
    unsigned* done          = cnt + 257;
    unsigned* cand          = (unsigned*)(ws + WS_CAND);
    unsigned* bmaxT         = (unsigned*)(ws + WS_BMAX);

    float* out0   = out;               // quantized_ste
    float* out1   = out + 8388608;     // quantized
    float* outL   = out + 16777216;    // q_loss, e_loss
    float* outIdx = out + 16777218;    // indices as f32

    // bf16 staging buffers live inside out0's region (dead until k3_out rewrites it)
    unsigned short* xbf = (unsigned short*)out0;
    unsigned short* ebf = xbf + (size_t)M_ROWS * DIM;

    hipLaunchKernelGGL(k1c,       dim3(2048), dim3(256), 0, stream, x, E, X, xbf, ebf, key, cnt);
    hipLaunchKernelGGL(kdot,      dim3(512),  dim3(512), 0, stream, xbf, ebf, bmaxT, ticket);
    hipLaunchKernelGGL(kgmax,     dim3(4096), dim3(256), 0, stream, bmaxT, cnt, cand);
    hipLaunchKernelGGL(krescore,  dim3(256),  dim3(512), 0, stream, x, E, X, cnt, cand, key);
    hipLaunchKernelGGL(k3_out,    dim3(2048), dim3(256), 0, stream, x, E, key, out0, out1, part, outIdx, done, outL);
}

// Round 17
// 575.899 us; speedup vs baseline: 2.5674x; 1.1055x over previous
//
#include <hip/hip_runtime.h>

#define M_ROWS 16384
#define DIM    512
#define NCODES 8192

// ws layout (bytes) — 9.2 MB total
#define WS_X     0          // 16384 f32
#define WS_KEY   65536      // 16384 u64 packed (dist_bits<<32)|code
#define WS_PART  196608     // 2048 f64
#define WS_CNT   212992     // 256 u32 bucket counters + ticket at [256]
#define WS_CAND  217088     // [256][1024] u32 rows
#define WS_BMAX  1265664    // bmaxT: [2048 tasks][64 rows][16] u32 = 8 MB
#define NPART    2048
#define BCAP     1024
#define ENC_MARG 84         // 84 * 3.05e-6 ≈ 2.56e-4 dot margin (validated)

typedef __attribute__((ext_vector_type(8))) short bh8;   // 8 bf16
typedef __attribute__((ext_vector_type(4))) float f32x4;

__device__ __forceinline__ unsigned short bfc(float f) {  // RNE f32->bf16 bits
    unsigned u = __float_as_uint(f);
    return (unsigned short)((u + 0x7fffu + ((u >> 16) & 1u)) >> 16);
}
__device__ __forceinline__ unsigned short enc16(float d) { // monotone fixed-point
    float v = (d + 0.1f) * 327680.0f;
    int iv = (int)v;
    iv = iv < 0 ? 0 : (iv > 65535 ? 65535 : iv);
    return (unsigned short)iv;
}
__device__ __forceinline__ void gload16(const void* g, void* l) {
    __builtin_amdgcn_global_load_lds(
        (const __attribute__((address_space(1))) unsigned int*)g,
        (__attribute__((address_space(3))) unsigned int*)l, 16, 0, 0);
}

// ---------------- K1c: init (folded k0) + rowsum (bitwise pairwise) + bf16 convert ----
__global__ __launch_bounds__(256) void k1c(
    const float* __restrict__ x, const float* __restrict__ E,
    float* __restrict__ X, unsigned short* __restrict__ xbf,
    unsigned short* __restrict__ ebf, unsigned long long* __restrict__ key,
    unsigned* __restrict__ cnt)
{
    const int gid = blockIdx.x * blockDim.x + threadIdx.x;
    // phase 0: init — key, 256 bucket counters, ticket
    if (gid < M_ROWS) key[gid] = ~0ull;
    if (gid <= 256) cnt[gid] = 0u;
    // phase 1: X = np.sum(x*x, axis=1), bitwise pairwise chain (validated)
    if (gid < M_ROWS) {
        const float* a = x + (size_t)gid * DIM;
        float b[4];
#pragma unroll
        for (int blk = 0; blk < 4; ++blk) {
            const float* p = a + blk * 128;
            float r[8];
#pragma unroll
            for (int j = 0; j < 8; ++j) r[j] = __fmul_rn(p[j], p[j]);
            for (int i = 8; i < 128; i += 8) {
#pragma unroll
                for (int j = 0; j < 8; ++j)
                    r[j] = __fadd_rn(r[j], __fmul_rn(p[i + j], p[i + j]));
            }
            b[blk] = __fadd_rn(__fadd_rn(__fadd_rn(r[0], r[1]), __fadd_rn(r[2], r[3])),
                               __fadd_rn(__fadd_rn(r[4], r[5]), __fadd_rn(r[6], r[7])));
        }
        X[gid] = __fadd_rn(__fadd_rn(b[0], b[1]), __fadd_rn(b[2], b[3]));
    }
    // phase 2: coalesced bf16 conversion (independent outputs)
    const int NX4 = M_ROWS * DIM / 4;
    const int NT  = NX4 + NCODES * DIM / 4;
    for (int i = gid; i < NT; i += gridDim.x * blockDim.x) {
        const float4* s; unsigned short* d; int o;
        if (i < NX4) { s = (const float4*)x; d = xbf; o = i; }
        else         { s = (const float4*)E; d = ebf; o = i - NX4; }
        float4 v = s[o];
        ushort4 u = make_ushort4(bfc(v.x), bfc(v.y), bfc(v.z), bfc(v.w));
        *(ushort4*)(d + (size_t)o * 4) = u;
    }
}

// ---------------- Kdot: round-13 version verbatim (measured optimum, 278 us) ----------
// 2048 tasks = 8 chunks (1024 codes) x 256 panels (64 rows), chunk-major ticket.
__global__ __launch_bounds__(512, 4) void kdot(
    const unsigned short* __restrict__ xbf, const unsigned short* __restrict__ ebf,
    unsigned* __restrict__ bmaxT, unsigned* __restrict__ ticket)
{
    __shared__ __align__(16) unsigned short As[64 * 512];  // 64 KiB, phys-swizzled
    __shared__ unsigned short lds_b16[64][32];             // 4 KiB result stage
    __shared__ int tsh;

    const int tid = threadIdx.x;
    const int w = tid >> 6, lane = tid & 63;
    const int lm = lane & 15, lh = lane >> 4;

    for (;;) {
        if (tid == 0) tsh = (int)atomicAdd(ticket, 1u);
        __syncthreads();                       // broadcast t; As/lds_b16 safe to reuse
        const int t = tsh;
        if (t >= 2048) break;
        const int chunk = t >> 8, panel = t & 255;
        const int row0 = panel * 64;
        const int c0 = chunk * 1024;

        // stage A panel (validated): linear LDS dest, inv-XOR-swizzled source
        for (int r8 = 0; r8 < 8; ++r8) {
            int q = r8 * 512 + tid;
            int row = q >> 6, cp = q & 63;
            gload16(xbf + (size_t)(row0 + row) * DIM + ((cp ^ (row & 7)) << 3),
                    (char*)As + (size_t)(r8 * 8192 + w * 1024));
        }
        __syncthreads();

        for (int pass = 0; pass < 4; ++pass) {
            const int cb = c0 + pass * 256 + w * 32;   // wave's 32-code group
            f32x4 acc[4][2];
            const f32x4 z = {0.f, 0.f, 0.f, 0.f};
#pragma unroll
            for (int mi = 0; mi < 4; ++mi) { acc[mi][0] = z; acc[mi][1] = z; }

            for (int kt = 0; kt < 16; ++kt) {
                bh8 a[4], b[2];
#pragma unroll
                for (int mi = 0; mi < 4; ++mi) {
                    int r = mi * 16 + lm;
                    int kc = kt * 4 + lh;
                    a[mi] = *(const bh8*)((const char*)As +
                                          (((r << 6) + (kc ^ (r & 7))) << 4));
                }
#pragma unroll
                for (int ni = 0; ni < 2; ++ni)
                    b[ni] = *(const bh8*)(ebf + (size_t)(cb + ni * 16 + lm) * DIM
                                          + kt * 32 + (lh << 3));
#pragma unroll
                for (int mi = 0; mi < 4; ++mi)
#pragma unroll
                    for (int ni = 0; ni < 2; ++ni)
                        acc[mi][ni] = __builtin_amdgcn_mfma_f32_16x16x32_bf16(
                            a[mi], b[ni], acc[mi][ni], 0, 0, 0);
            }
            // per-(row, 32-grp) max; identical fmax tree + 16-lane shfl reduce
            const int gidx = pass * 8 + w;             // 32-code group within chunk
#pragma unroll
            for (int mi = 0; mi < 4; ++mi)
#pragma unroll
                for (int reg = 0; reg < 4; ++reg) {
                    float m = fmaxf(acc[mi][0][reg], acc[mi][1][reg]);
#pragma unroll
                    for (int off = 1; off < 16; off <<= 1)
                        m = fmaxf(m, __shfl_xor(m, off));
                    if (lm == 0)
                        lds_b16[mi * 16 + lh * 4 + reg][gidx] = enc16(m);
                }
        }
        __syncthreads();
        // dense coalesced store: 4 KB contiguous per task (full lines, no RMW)
        const unsigned* lb = (const unsigned*)&lds_b16[0][0];
#pragma unroll
        for (int k = 0; k < 2; ++k) {
            int i = k * 512 + tid;
            bmaxT[(size_t)t * 1024 + i] = lb[i];
        }
    }
}

// ---------------- Kgmax: round-13 version verbatim ----------------
__global__ __launch_bounds__(256) void kgmax(const unsigned* __restrict__ bmaxT,
                                             unsigned* __restrict__ cnt,
                                             unsigned* __restrict__ cand) {
    int gt = blockIdx.x * blockDim.x + threadIdx.x;
    int row = gt >> 6, lane = gt & 63;
    if (row >= M_ROWS) return;
    const int panel = row >> 6, r = row & 63;
    const int c0 = lane >> 4, gl = lane & 15;
    unsigned w0 = bmaxT[(size_t)(((c0    ) * 256 + panel) * 64 + r) * 16 + gl];
    unsigned w1 = bmaxT[(size_t)(((c0 + 4) * 256 + panel) * 64 + r) * 16 + gl];
    unsigned e[4] = {w0 & 0xffffu, w0 >> 16, w1 & 0xffffu, w1 >> 16};
    int      g[4] = {c0 * 32 + 2 * gl, c0 * 32 + 2 * gl + 1,
                     (c0 + 4) * 32 + 2 * gl, (c0 + 4) * 32 + 2 * gl + 1};
    unsigned m = max(max(e[0], e[1]), max(e[2], e[3]));
#pragma unroll
    for (int off = 1; off < 64; off <<= 1) m = max(m, (unsigned)__shfl_xor((int)m, off));
    unsigned th = (m > ENC_MARG) ? m - ENC_MARG : 0u;
#pragma unroll
    for (int k = 0; k < 4; ++k)
        if (e[k] >= th) {
            unsigned pos = atomicAdd(cnt + g[k], 1u);
            if (pos < BCAP) cand[g[k] * BCAP + pos] = (unsigned)row;
        }
}

// ---------------- Krescore: 1 block/bucket, coalesced staging, exact f32 chain ----------
// FMA chain (d=0..511, single acc) bitwise-identical to the validated sequence.
__global__ __launch_bounds__(512, 2) void krescore(
    const float* __restrict__ x, const float* __restrict__ E,
    const float* __restrict__ Xs, const unsigned* __restrict__ cnt,
    const unsigned* __restrict__ cand, unsigned long long* __restrict__ key)
{
    __shared__ float lds_e[512][33];   // 67.5 KiB padded: reads conflict-free
    const int b = blockIdx.x;
    const int t = threadIdx.x;
    {   // coalesced staging: consecutive threads read consecutive 16B of the slice
        const float4* Eb = (const float4*)(E + (size_t)b * 32 * DIM);  // 4096 float4
#pragma unroll
        for (int i = 0; i < 8; ++i) {
            int o = i * 512 + t;            // linear float4 index
            int r = o >> 7, c4 = o & 127;   // row, float4-col
            float4 v = Eb[o];
            lds_e[c4 * 4 + 0][r] = v.x; lds_e[c4 * 4 + 1][r] = v.y;
            lds_e[c4 * 4 + 2][r] = v.z; lds_e[c4 * 4 + 3][r] = v.w;
        }
    }
    __syncthreads();
    unsigned nb = cnt[b]; if (nb > BCAP) nb = BCAP;
    const int hw = t >> 5, l = t & 31;              // 16 lane-groups of 32
    for (unsigned p = (unsigned)hw; p < nb; p += 16) {
        int row = (int)cand[b * BCAP + p];
        const float4* __restrict__ xr = (const float4*)(x + (size_t)row * DIM);
        float acc = 0.f;
        for (int d0 = 0; d0 < 128; d0 += 8) {
            float4 xv[8];
#pragma unroll
            for (int j = 0; j < 8; ++j) xv[j] = xr[d0 + j];
#pragma unroll
            for (int j = 0; j < 8; ++j) {
                int d = (d0 + j) * 4;
                acc = __fmaf_rn(xv[j].x, lds_e[d + 0][l], acc);
                acc = __fmaf_rn(xv[j].y, lds_e[d + 1][l], acc);
                acc = __fmaf_rn(xv[j].z, lds_e[d + 2][l], acc);
                acc = __fmaf_rn(xv[j].w, lds_e[d + 3][l], acc);
            }
        }
        float dist = __fsub_rn(Xs[row], __fmul_rn(2.0f, acc));
        unsigned long long k =
            ((unsigned long long)__float_as_uint(dist) << 32) | (unsigned)(b * 32 + l);
#pragma unroll
        for (int off = 1; off < 32; off <<= 1) {
            unsigned long long o = __shfl_xor(k, off);
            k = o < k ? o : k;
        }
        if (l == 0) atomicMin(key + row, k);
    }
}

// ---------------- K3: gather outputs + loss partials + indices (round-13 verbatim) -----
__global__ __launch_bounds__(256) void k3_out(
    const float* __restrict__ x, const float* __restrict__ E,
    const unsigned long long* __restrict__ key, float* __restrict__ out0,
    float* __restrict__ out1, double* __restrict__ part,
    float* __restrict__ outIdx)
{
    const int n4 = M_ROWS * (DIM / 4);
    double loc = 0.0;
    for (int i4 = blockIdx.x * blockDim.x + threadIdx.x; i4 < n4;
         i4 += gridDim.x * blockDim.x) {
        int row = i4 >> 7;
        int d4  = i4 & 127;
        int idx = (int)(key[row] & 8191ull);
        if (d4 == 0) outIdx[row] = (float)idx;   // fold k2b: exactly once per row
        float4 xv = *(const float4*)(x + (size_t)i4 * 4);
        float4 qv = *(const float4*)(E + (size_t)idx * DIM + d4 * 4);
        float4 o0;
        float dx0 = __fsub_rn(qv.x, xv.x);
        float dx1 = __fsub_rn(qv.y, xv.y);
        float dx2 = __fsub_rn(qv.z, xv.z);
        float dx3 = __fsub_rn(qv.w, xv.w);
        o0.x = __fadd_rn(xv.x, dx0);
        o0.y = __fadd_rn(xv.y, dx1);
        o0.z = __fadd_rn(xv.z, dx2);
        o0.w = __fadd_rn(xv.w, dx3);
        *(float4*)(out0 + (size_t)i4 * 4) = o0;
        *(float4*)(out1 + (size_t)i4 * 4) = qv;
        loc += (double)__fmul_rn(dx0, dx0) + (double)__fmul_rn(dx1, dx1)
             + (double)__fmul_rn(dx2, dx2) + (double)__fmul_rn(dx3, dx3);
    }
#pragma unroll
    for (int off = 32; off > 0; off >>= 1) loc += __shfl_down(loc, off);
    __shared__ double wsum[4];
    int lane = threadIdx.x & 63, wid = threadIdx.x >> 6;
    if (lane == 0) wsum[wid] = loc;
    __syncthreads();
    if (threadIdx.x == 0)
        part[blockIdx.x] = (wsum[0] + wsum[1]) + (wsum[2] + wsum[3]);
}

// ---------------- K4: finalize losses (separate — fence-free) ----------------
__global__ void k4_final(const double* __restrict__ part, float* __restrict__ outL) {
    __shared__ double s[256];
    double loc = 0.0;
    for (int i = threadIdx.x; i < NPART; i += 256) loc += part[i];
    s[threadIdx.x] = loc;
    __syncthreads();
    for (int st = 128; st > 0; st >>= 1) {
        if (threadIdx.x < st) s[threadIdx.x] += s[threadIdx.x + st];
        __syncthreads();
    }
    if (threadIdx.x == 0) {
        float m = (float)(s[0] / 8388608.0);
        outL[0] = m;
        outL[1] = m;
    }
}

extern "C" void kernel_launch(void* const* d_in, const int* in_sizes, int n_in,
                              void* d_out, int out_size, void* d_ws, size_t ws_size,
                              hipStream_t stream) {
    const float* x = (const float*)d_in[0];
    const float* E = (const float*)d_in[1];
    float* out = (float*)d_out;
    char* ws = (char*)d_ws;

    float* X                = (float*)(ws + WS_X);
    unsigned long long* key = (unsigned long long*)(ws + WS_KEY);
    double* part            = (double*)(ws + WS_PART);
    unsigned* cnt           = (unsigned*)(ws + WS_CNT);
    unsigned* ticket        = cnt + 256;
    unsigned* cand          = (unsigned*)(ws + WS_CAND);
    unsigned* bmaxT         = (unsigned*)(ws + WS_BMAX);

    float* out0   = out;               // quantized_ste
    float* out1   = out + 8388608;     // quantized
    float* outL   = out + 16777216;    // q_loss, e_loss
    float* outIdx = out + 16777218;    // indices as f32

    // bf16 staging buffers live inside out0's region (dead until k3_out rewrites it)
    unsigned short* xbf = (unsigned short*)out0;
    unsigned short* ebf = xbf + (size_t)M_ROWS * DIM;

    hipLaunchKernelGGL(k1c,       dim3(2048), dim3(256), 0, stream, x, E, X, xbf, ebf, key, cnt);
    hipLaunchKernelGGL(kdot,      dim3(512),  dim3(512), 0, stream, xbf, ebf, bmaxT, ticket);
    hipLaunchKernelGGL(kgmax,     dim3(4096), dim3(256), 0, stream, bmaxT, cnt, cand);
    hipLaunchKernelGGL(krescore,  dim3(256),  dim3(512), 0, stream, x, E, X, cnt, cand, key);
    hipLaunchKernelGGL(k3_out,    dim3(2048), dim3(256), 0, stream, x, E, key, out0, out1, part, outIdx);
    hipLaunchKernelGGL(k4_final,  dim3(1),    dim3(256), 0, stream, part, outL);
}